// Round 1
// baseline (5778.044 us; speedup 1.0000x reference)
//
#include <hip/hip_runtime.h>
#include <math.h>

// Problem constants
#define BB 4
#define TT 2048
#define DD 1024
#define HH 16
#define QKD 64
#define MM (BB*TT)          // 8192
#define NN 1024             // H*QK == D

// ---------------------------------------------------------------------------
// Tiled fp32 GEMM: C[M,N] = A[M,K] @ W[K,N] + bias[N]
// M=8192, K=1024, N=1024. 64x64 tile, BK=16, 256 threads, 4x4 per thread.
// mode 0: plain row-major output.  mode 1: remap cols/rows to (B,H,T,QK).
// ---------------------------------------------------------------------------
__global__ __launch_bounds__(256) void gemm_kernel(
    const float* __restrict__ A, const float* __restrict__ W,
    const float* __restrict__ bias, float* __restrict__ out, int mode)
{
    const int K = 1024, N = 1024;
    __shared__ float As[16][68];   // [k][m], padded for alignment + banks
    __shared__ float Bs[16][68];   // [k][n]

    const int tid = threadIdx.x;
    const int tx = tid & 15, ty = tid >> 4;
    const int m0 = blockIdx.y * 64, n0 = blockIdx.x * 64;

    // loader indices
    const int arow = tid >> 2;            // 0..63
    const int ak4  = (tid & 3) << 2;      // 0,4,8,12
    const int bkk  = tid >> 4;            // 0..15
    const int bj4  = (tid & 15) << 2;     // 0..60

    float acc[4][4] = {};

    for (int k0 = 0; k0 < K; k0 += 16) {
        float4 va = *(const float4*)&A[(size_t)(m0 + arow) * K + k0 + ak4];
        float4 vb = *(const float4*)&W[(size_t)(k0 + bkk) * N + n0 + bj4];
        As[ak4 + 0][arow] = va.x;
        As[ak4 + 1][arow] = va.y;
        As[ak4 + 2][arow] = va.z;
        As[ak4 + 3][arow] = va.w;
        *(float4*)&Bs[bkk][bj4] = vb;
        __syncthreads();
        #pragma unroll
        for (int kk = 0; kk < 16; kk++) {
            float4 av = *(const float4*)&As[kk][ty << 2];
            float4 bv = *(const float4*)&Bs[kk][tx << 2];
            float a4[4] = {av.x, av.y, av.z, av.w};
            float b4[4] = {bv.x, bv.y, bv.z, bv.w};
            #pragma unroll
            for (int i = 0; i < 4; i++)
                #pragma unroll
                for (int j = 0; j < 4; j++)
                    acc[i][j] += a4[i] * b4[j];
        }
        __syncthreads();
    }

    #pragma unroll
    for (int i = 0; i < 4; i++) {
        int m = m0 + (ty << 2) + i;
        #pragma unroll
        for (int j = 0; j < 4; j++) {
            int n = n0 + (tx << 2) + j;
            float v = acc[i][j] + bias[n];
            if (mode == 0) {
                out[(size_t)m * N + n] = v;
            } else {
                int b = m >> 11, t = m & 2047;
                int h = n >> 6,  d = n & 63;
                out[(size_t)(((b * HH + h) * TT) + t) * QKD + d] = v;
            }
        }
    }
}

// ---------------------------------------------------------------------------
// Fused RMSNorm + RoPE, in place on (B,H,T,QK) layout. One wave per row.
// qmul folds the 1/sqrt(QK) logits scaling into q.
// ---------------------------------------------------------------------------
__global__ __launch_bounds__(256) void norm_rope_kernel(
    float* __restrict__ x, const float* __restrict__ scale,
    const int* __restrict__ positions, float qmul)
{
    const int row  = blockIdx.x * 4 + (threadIdx.x >> 6);
    const int lane = threadIdx.x & 63;
    const int t  = row & 2047;
    const int bh = row >> 11;
    const int b  = bh >> 4;

    float v = x[(size_t)row * 64 + lane];
    float ss = v * v;
    #pragma unroll
    for (int o = 32; o >= 1; o >>= 1) ss += __shfl_xor(ss, o);
    float y = v * rsqrtf(ss * (1.0f / 64.0f) + 1e-6f) * (1.0f + scale[lane]);

    int pos = positions[b * TT + t];
    int j = lane & 31;
    float ts  = powf(10000.0f, (float)j * (1.0f / 32.0f));
    float ang = (float)pos / ts;
    float s = sinf(ang), c = cosf(ang);
    float partner = __shfl_xor(y, 32);
    float outv = (lane < 32) ? (y * c - partner * s)
                             : (y * c + partner * s);
    x[(size_t)row * 64 + lane] = outv * qmul;
}

// ---------------------------------------------------------------------------
// Flash attention, causal. One block per (qtile=64 queries, h, b).
// 256 threads: thread t -> query qi=t>>2, key/col sub-range sub=t&3 (16 wide).
// LDS tiles are stride-64 with row-rotate swizzle ((c+r)&63) so all four fit
// in exactly 64 KiB while keeping <=2-way bank aliasing (free on gfx950).
// ---------------------------------------------------------------------------
#define SWZ(arr, r, c) arr[((r) << 6) | (((c) + (r)) & 63)]

__global__ __launch_bounds__(256) void attn_kernel(
    const float* __restrict__ qh, const float* __restrict__ kh,
    const float* __restrict__ vh, const float* __restrict__ head_scale,
    float* __restrict__ out)
{
    __shared__ float Qs[4096], Ks[4096], Vs[4096], Ps[4096];

    const int b = blockIdx.z, h = blockIdx.y, qt = blockIdx.x;
    const int t0 = qt * 64;
    const int tid = threadIdx.x;

    const size_t bh_off = (size_t)(b * HH + h) * TT * QKD;
    const float* qbase = qh + bh_off + (size_t)t0 * QKD;
    const float* kbase = kh + bh_off;
    const float* vbase = vh + bh_off;

    for (int idx = tid; idx < 4096; idx += 256) {
        int r = idx >> 6, c = idx & 63;
        SWZ(Qs, r, c) = qbase[idx];
    }

    const int qi   = tid >> 2;
    const int sub  = tid & 3;
    const int kj0  = sub << 4;   // owned key range base (16 keys)
    const int dcol = sub << 4;   // owned output-col range base (16 cols)

    float m_run = -INFINITY, l_run = 0.0f;
    float o[16];
    #pragma unroll
    for (int c = 0; c < 16; c++) o[c] = 0.0f;

    for (int j0 = 0; j0 <= t0; j0 += 64) {
        for (int idx = tid; idx < 4096; idx += 256) {
            int r = idx >> 6, c = idx & 63;
            SWZ(Ks, r, c) = kbase[(size_t)j0 * 64 + idx];
            SWZ(Vs, r, c) = vbase[(size_t)j0 * 64 + idx];
        }
        __syncthreads();

        // scores for this thread's 16 keys
        float s_acc[16];
        #pragma unroll
        for (int jj = 0; jj < 16; jj++) s_acc[jj] = 0.0f;
        for (int d = 0; d < 64; d++) {
            float qv = SWZ(Qs, qi, d);
            #pragma unroll
            for (int jj = 0; jj < 16; jj++)
                s_acc[jj] += qv * SWZ(Ks, kj0 + jj, d);
        }
        // causal mask (only fires on the diagonal tile)
        if (j0 + 63 > t0 + qi) {
            #pragma unroll
            for (int jj = 0; jj < 16; jj++)
                if (j0 + kj0 + jj > t0 + qi) s_acc[jj] = -INFINITY;
        }

        // online softmax across the 4 threads sharing this query
        float mt = -INFINITY;
        #pragma unroll
        for (int jj = 0; jj < 16; jj++) mt = fmaxf(mt, s_acc[jj]);
        mt = fmaxf(mt, __shfl_xor(mt, 1));
        mt = fmaxf(mt, __shfl_xor(mt, 2));
        float m_new = fmaxf(m_run, mt);
        float alpha = expf(m_run - m_new);   // exp(-inf)=0 on first tile
        float psum = 0.0f;
        #pragma unroll
        for (int jj = 0; jj < 16; jj++) {
            float p = expf(s_acc[jj] - m_new);
            SWZ(Ps, qi, kj0 + jj) = p;
            psum += p;
        }
        psum += __shfl_xor(psum, 1);
        psum += __shfl_xor(psum, 2);
        l_run = l_run * alpha + psum;
        m_run = m_new;
        __syncthreads();

        // O update: this thread covers (qi, dcol..dcol+15) over all 64 keys
        #pragma unroll
        for (int c = 0; c < 16; c++) o[c] *= alpha;
        for (int j = 0; j < 64; j++) {
            float p = SWZ(Ps, qi, j);
            #pragma unroll
            for (int c = 0; c < 16; c++)
                o[c] += p * SWZ(Vs, j, dcol + c);
        }
        __syncthreads();
    }

    const float hs = 1.0f + head_scale[h];
    const float inv_l = 1.0f / l_run;
    const int tq = t0 + qi;
    float* op = out + ((size_t)(b * TT + tq) * NN) + h * QKD + dcol;
    #pragma unroll
    for (int c = 0; c < 16; c++) op[c] = o[c] * inv_l * hs;
}

// ---------------------------------------------------------------------------
extern "C" void kernel_launch(void* const* d_in, const int* in_sizes, int n_in,
                              void* d_out, int out_size, void* d_ws, size_t ws_size,
                              hipStream_t stream)
{
    const float* q          = (const float*)d_in[0];
    const float* kv         = (const float*)d_in[1];
    /* d_in[2] = mask (causal tril) -- handled analytically */
    const int*   qpos       = (const int*)d_in[3];
    const int*   kpos       = (const int*)d_in[4];
    const float* Wq         = (const float*)d_in[5];
    const float* bq         = (const float*)d_in[6];
    const float* Wk         = (const float*)d_in[7];
    const float* bk         = (const float*)d_in[8];
    const float* Wv         = (const float*)d_in[9];
    const float* bv         = (const float*)d_in[10];
    const float* q_scale    = (const float*)d_in[11];
    const float* k_scale    = (const float*)d_in[12];
    const float* head_scale = (const float*)d_in[13];
    const float* Wo         = (const float*)d_in[14];
    const float* bo         = (const float*)d_in[15];
    float* out = (float*)d_out;

    float* ws   = (float*)d_ws;
    float* qh   = ws;                  // (B,H,T,QK)
    float* khp  = ws + 8388608;        // (B,H,T,QK)
    float* vhp  = ws + 16777216;       // (B,H,T,QK)
    float* attn = ws + 25165824;       // (B,T,H*QK)

    dim3 gblk(256);
    dim3 ggrid(NN / 64, MM / 64);

    // QKV projections (epilogue remaps to (B,H,T,QK))
    gemm_kernel<<<ggrid, gblk, 0, stream>>>(q,  Wq, bq, qh,  1);
    gemm_kernel<<<ggrid, gblk, 0, stream>>>(kv, Wk, bk, khp, 1);
    gemm_kernel<<<ggrid, gblk, 0, stream>>>(kv, Wv, bv, vhp, 1);

    // RMSNorm + RoPE (q also gets 1/sqrt(QK))
    norm_rope_kernel<<<(BB * HH * TT) / 4, 256, 0, stream>>>(qh,  q_scale, qpos, 0.125f);
    norm_rope_kernel<<<(BB * HH * TT) / 4, 256, 0, stream>>>(khp, k_scale, kpos, 1.0f);

    // causal flash attention + head_scale, writes (B,T,H*QK)
    attn_kernel<<<dim3(TT / 64, HH, BB), 256, 0, stream>>>(qh, khp, vhp, head_scale, attn);

    // output projection
    gemm_kernel<<<ggrid, gblk, 0, stream>>>(attn, Wo, bo, out, 0);
}

// Round 2
// 1491.253 us; speedup vs baseline: 3.8746x; 3.8746x over previous
//
#include <hip/hip_runtime.h>
#include <math.h>

// Problem constants
#define BB 4
#define TT 2048
#define DD 1024
#define HH 16
#define QKD 64
#define MM (BB*TT)          // 8192
#define NN 1024             // H*QK == D

typedef unsigned short u16;
typedef __attribute__((ext_vector_type(8))) short short8;   // 8 bf16 = 4 VGPRs
typedef __attribute__((ext_vector_type(4))) float float4v;  // MFMA C/D

// fp32 -> bf16 round-to-nearest-even
__device__ inline u16 f2bf(float f) {
    union { float f; unsigned u; } v; v.f = f;
    unsigned r = (v.u + 0x7FFFu + ((v.u >> 16) & 1u)) >> 16;
    return (u16)r;
}

// ---------------------------------------------------------------------------
// Tiled fp32 GEMM: C[M,N] = A[M,K] @ W[K,N] + bias[N]
// mode 0: row-major fp32. mode 1: (B,H,T,QK) fp32. mode 2: (B,H,T,QK) bf16.
// ---------------------------------------------------------------------------
__global__ __launch_bounds__(256) void gemm_kernel(
    const float* __restrict__ A, const float* __restrict__ W,
    const float* __restrict__ bias, float* __restrict__ out, int mode)
{
    const int K = 1024, N = 1024;
    __shared__ float As[16][68];
    __shared__ float Bs[16][68];

    const int tid = threadIdx.x;
    const int tx = tid & 15, ty = tid >> 4;
    const int m0 = blockIdx.y * 64, n0 = blockIdx.x * 64;

    const int arow = tid >> 2;
    const int ak4  = (tid & 3) << 2;
    const int bkk  = tid >> 4;
    const int bj4  = (tid & 15) << 2;

    float acc[4][4] = {};

    for (int k0 = 0; k0 < K; k0 += 16) {
        float4 va = *(const float4*)&A[(size_t)(m0 + arow) * K + k0 + ak4];
        float4 vb = *(const float4*)&W[(size_t)(k0 + bkk) * N + n0 + bj4];
        As[ak4 + 0][arow] = va.x;
        As[ak4 + 1][arow] = va.y;
        As[ak4 + 2][arow] = va.z;
        As[ak4 + 3][arow] = va.w;
        *(float4*)&Bs[bkk][bj4] = vb;
        __syncthreads();
        #pragma unroll
        for (int kk = 0; kk < 16; kk++) {
            float4 av = *(const float4*)&As[kk][ty << 2];
            float4 bv = *(const float4*)&Bs[kk][tx << 2];
            float a4[4] = {av.x, av.y, av.z, av.w};
            float b4[4] = {bv.x, bv.y, bv.z, bv.w};
            #pragma unroll
            for (int i = 0; i < 4; i++)
                #pragma unroll
                for (int j = 0; j < 4; j++)
                    acc[i][j] += a4[i] * b4[j];
        }
        __syncthreads();
    }

    #pragma unroll
    for (int i = 0; i < 4; i++) {
        int m = m0 + (ty << 2) + i;
        #pragma unroll
        for (int j = 0; j < 4; j++) {
            int n = n0 + (tx << 2) + j;
            float v = acc[i][j] + bias[n];
            if (mode == 0) {
                out[(size_t)m * N + n] = v;
            } else {
                int b = m >> 11, t = m & 2047;
                int h = n >> 6,  d = n & 63;
                size_t o = (size_t)(((b * HH + h) * TT) + t) * QKD + d;
                if (mode == 1) out[o] = v;
                else           ((u16*)out)[o] = f2bf(v);
            }
        }
    }
}

// ---------------------------------------------------------------------------
// Fused RMSNorm + RoPE on (B,H,T,QK): fp32 in -> bf16 out. One wave per row.
// qmul folds 1/sqrt(QK) AND log2(e) (attention softmax runs in exp2 domain).
// ---------------------------------------------------------------------------
__global__ __launch_bounds__(256) void norm_rope_kernel(
    const float* __restrict__ xin, u16* __restrict__ xout,
    const float* __restrict__ scale, const int* __restrict__ positions, float qmul)
{
    const int row  = blockIdx.x * 4 + (threadIdx.x >> 6);
    const int lane = threadIdx.x & 63;
    const int t  = row & 2047;
    const int bh = row >> 11;
    const int b  = bh >> 4;

    float v = xin[(size_t)row * 64 + lane];
    float ss = v * v;
    #pragma unroll
    for (int o = 32; o >= 1; o >>= 1) ss += __shfl_xor(ss, o);
    float y = v * rsqrtf(ss * (1.0f / 64.0f) + 1e-6f) * (1.0f + scale[lane]);

    int pos = positions[b * TT + t];
    int j = lane & 31;
    float ts  = powf(10000.0f, (float)j * (1.0f / 32.0f));
    float ang = (float)pos / ts;
    float s = sinf(ang), c = cosf(ang);
    float partner = __shfl_xor(y, 32);
    float outv = (lane < 32) ? (y * c - partner * s)
                             : (y * c + partner * s);
    xout[(size_t)row * 64 + lane] = f2bf(outv * qmul);
}

// ---------------------------------------------------------------------------
// MFMA flash attention, causal. Block = (64 queries, h, b); 4 waves, each
// owning 16 queries. 16x16x32 bf16 MFMA for QK^T and PV; fp32 online softmax
// entirely in registers (C-layout rows live in one 16-lane group).
// LDS rows are 72 elements (144 B): b128 frag reads land 2-way = free.
// ---------------------------------------------------------------------------
#define LSTR 72

__global__ __launch_bounds__(256) void attn_mfma(
    const u16* __restrict__ qh, const u16* __restrict__ kh,
    const u16* __restrict__ vh, const float* __restrict__ head_scale,
    float* __restrict__ out)
{
    __shared__ u16 Ks[64 * LSTR];      // K tile, row-major [key][d]
    __shared__ u16 Vt[64 * LSTR];      // V tile transposed [d][key]
    __shared__ u16 Ps[4][16 * LSTR];   // per-wave P round-trip [q][key]

    const int b = blockIdx.z, h = blockIdx.y, qt = blockIdx.x;
    const int t0 = qt * 64;
    const int tid  = threadIdx.x;
    const int wave = tid >> 6, lane = tid & 63;
    const int l15 = lane & 15, lg = lane >> 4;

    const size_t bh_off = (size_t)(b * HH + h) * TT * QKD;
    const u16* qbh = qh + bh_off;
    const u16* kbh = kh + bh_off;
    const u16* vbh = vh + bh_off;

    // Q A-fragments in registers for the whole block (A: m=lane&15, k=lg*8+j)
    short8 qfrag[2];
    #pragma unroll
    for (int kc = 0; kc < 2; kc++)
        qfrag[kc] = *(const short8*)(qbh + (size_t)(t0 + wave * 16 + l15) * QKD
                                      + kc * 32 + lg * 8);

    float4v o_acc[4];
    #pragma unroll
    for (int nt = 0; nt < 4; nt++) o_acc[nt] = (float4v){0.f, 0.f, 0.f, 0.f};
    float m_run[4] = {-INFINITY, -INFINITY, -INFINITY, -INFINITY};
    float l_run[4] = {0.f, 0.f, 0.f, 0.f};

    for (int j0 = 0; j0 <= t0; j0 += 64) {
        // ---- stage K (row-major) and V (transposed), bf16 ----
        #pragma unroll
        for (int r = 0; r < 2; r++) {
            int idx = r * 256 + tid;             // 0..511
            int row = idx >> 3, cb = (idx & 7) * 8;
            short8 k8 = *(const short8*)(kbh + (size_t)(j0 + row) * QKD + cb);
            *(short8*)&Ks[row * LSTR + cb] = k8;

            int j   = tid & 63;
            int dv0 = (tid >> 6) * 8 + r * 32;
            short8 v8 = *(const short8*)(vbh + (size_t)(j0 + j) * QKD + dv0);
            #pragma unroll
            for (int i = 0; i < 8; i++)
                Vt[(dv0 + i) * LSTR + j] = (u16)v8[i];
        }
        __syncthreads();

        // ---- S = Q K^T (log2 domain; scale folded into q) ----
        float4v sarr[4];
        #pragma unroll
        for (int nt = 0; nt < 4; nt++) {
            float4v s = (float4v){0.f, 0.f, 0.f, 0.f};
            #pragma unroll
            for (int kc = 0; kc < 2; kc++) {
                short8 bfrag = *(const short8*)&Ks[(nt * 16 + l15) * LSTR + kc * 32 + lg * 8];
                s = __builtin_amdgcn_mfma_f32_16x16x32_bf16(qfrag[kc], bfrag, s, 0, 0, 0);
            }
            sarr[nt] = s;
        }

        // ---- causal mask (diagonal tile only) ----
        const int qbase = t0 + wave * 16 + lg * 4;
        if (j0 == t0) {
            #pragma unroll
            for (int nt = 0; nt < 4; nt++) {
                int jkey = j0 + nt * 16 + l15;
                #pragma unroll
                for (int r = 0; r < 4; r++)
                    if (jkey > qbase + r) sarr[nt][r] = -INFINITY;
            }
        }

        // ---- online softmax, fp32 in registers ----
        float alpha[4], rowsum[4];
        #pragma unroll
        for (int r = 0; r < 4; r++) {
            float m = fmaxf(fmaxf(sarr[0][r], sarr[1][r]), fmaxf(sarr[2][r], sarr[3][r]));
            m = fmaxf(m, __shfl_xor(m, 1));
            m = fmaxf(m, __shfl_xor(m, 2));
            m = fmaxf(m, __shfl_xor(m, 4));
            m = fmaxf(m, __shfl_xor(m, 8));
            float m_new = fmaxf(m_run[r], m);
            alpha[r] = exp2f(m_run[r] - m_new);   // first tile: exp2(-inf)=0
            m_run[r] = m_new;
            rowsum[r] = 0.f;
        }
        u16* pw = Ps[wave];
        #pragma unroll
        for (int nt = 0; nt < 4; nt++) {
            #pragma unroll
            for (int r = 0; r < 4; r++) {
                float p = exp2f(sarr[nt][r] - m_run[r]);
                rowsum[r] += p;
                pw[(lg * 4 + r) * LSTR + nt * 16 + l15] = f2bf(p);
            }
        }
        #pragma unroll
        for (int r = 0; r < 4; r++) {
            float rs = rowsum[r];
            rs += __shfl_xor(rs, 1);
            rs += __shfl_xor(rs, 2);
            rs += __shfl_xor(rs, 4);
            rs += __shfl_xor(rs, 8);
            l_run[r] = l_run[r] * alpha[r] + rs;
        }
        #pragma unroll
        for (int nt = 0; nt < 4; nt++)
            #pragma unroll
            for (int r = 0; r < 4; r++)
                o_acc[nt][r] *= alpha[r];

        // ---- O += P V  (P via LDS round-trip into A layout) ----
        short8 pf[2];
        #pragma unroll
        for (int kc = 0; kc < 2; kc++)
            pf[kc] = *(const short8*)&pw[l15 * LSTR + kc * 32 + lg * 8];
        #pragma unroll
        for (int nt = 0; nt < 4; nt++) {
            #pragma unroll
            for (int kc = 0; kc < 2; kc++) {
                short8 vfrag = *(const short8*)&Vt[(nt * 16 + l15) * LSTR + kc * 32 + lg * 8];
                o_acc[nt] = __builtin_amdgcn_mfma_f32_16x16x32_bf16(pf[kc], vfrag, o_acc[nt], 0, 0, 0);
            }
        }
        __syncthreads();
    }

    // ---- epilogue: /l, *(1+head_scale), write (B,T,H*QK) fp32 ----
    const float hs = 1.0f + head_scale[h];
    #pragma unroll
    for (int r = 0; r < 4; r++) {
        const int q = t0 + wave * 16 + lg * 4 + r;
        const float f = hs / l_run[r];
        float* op = out + ((size_t)(b * TT + q) * NN) + h * QKD + l15;
        #pragma unroll
        for (int nt = 0; nt < 4; nt++)
            op[nt * 16] = o_acc[nt][r] * f;
    }
}

// ---------------------------------------------------------------------------
extern "C" void kernel_launch(void* const* d_in, const int* in_sizes, int n_in,
                              void* d_out, int out_size, void* d_ws, size_t ws_size,
                              hipStream_t stream)
{
    const float* q          = (const float*)d_in[0];
    const float* kv         = (const float*)d_in[1];
    /* d_in[2] = causal mask -- handled analytically */
    const int*   qpos       = (const int*)d_in[3];
    const int*   kpos       = (const int*)d_in[4];
    const float* Wq         = (const float*)d_in[5];
    const float* bq         = (const float*)d_in[6];
    const float* Wk         = (const float*)d_in[7];
    const float* bk         = (const float*)d_in[8];
    const float* Wv         = (const float*)d_in[9];
    const float* bv         = (const float*)d_in[10];
    const float* q_scale    = (const float*)d_in[11];
    const float* k_scale    = (const float*)d_in[12];
    const float* head_scale = (const float*)d_in[13];
    const float* Wo         = (const float*)d_in[14];
    const float* bo         = (const float*)d_in[15];
    float* out = (float*)d_out;

    // workspace layout (bytes):
    //   [0,        33554432)  qh_f32  -- later reused as attn fp32
    //   [33554432, 67108864)  kh_f32
    //   [67108864, 83886080)  vh_bf16
    //   [83886080, 100663296) qh_bf16
    //   [100663296,117440512) kh_bf16
    float* ws    = (float*)d_ws;
    float* qh_f  = ws;
    float* kh_f  = ws + 8388608;
    u16*   vh_b  = (u16*)((char*)d_ws + 67108864);
    u16*   qh_b  = (u16*)((char*)d_ws + 83886080);
    u16*   kh_b  = (u16*)((char*)d_ws + 100663296);
    float* attn  = ws;   // aliases qh_f (dead after norm_rope)

    dim3 gblk(256);
    dim3 ggrid(NN / 64, MM / 64);

    // QKV projections
    gemm_kernel<<<ggrid, gblk, 0, stream>>>(q,  Wq, bq, qh_f, 1);
    gemm_kernel<<<ggrid, gblk, 0, stream>>>(kv, Wk, bk, kh_f, 1);
    gemm_kernel<<<ggrid, gblk, 0, stream>>>(kv, Wv, bv, (float*)vh_b, 2);

    // RMSNorm + RoPE -> bf16; q also gets 1/sqrt(QK) * log2(e)
    const float QMUL = 0.125f * 1.44269504088896340736f;
    norm_rope_kernel<<<(BB * HH * TT) / 4, 256, 0, stream>>>(qh_f, qh_b, q_scale, qpos, QMUL);
    norm_rope_kernel<<<(BB * HH * TT) / 4, 256, 0, stream>>>(kh_f, kh_b, k_scale, kpos, 1.0f);

    // causal MFMA flash attention + head_scale -> (B,T,H*QK) fp32
    attn_mfma<<<dim3(TT / 64, HH, BB), 256, 0, stream>>>(qh_b, kh_b, vh_b, head_scale, attn);

    // output projection
    gemm_kernel<<<ggrid, gblk, 0, stream>>>(attn, Wo, bo, out, 0);
}

// Round 3
// 527.275 us; speedup vs baseline: 10.9583x; 2.8282x over previous
//
#include <hip/hip_runtime.h>
#include <math.h>

// Problem constants
#define BB 4
#define TT 2048
#define DD 1024
#define HH 16
#define QKD 64
#define MM (BB*TT)          // 8192
#define NN 1024             // H*QK == D
#define KK 1024

typedef unsigned short u16;
typedef __attribute__((ext_vector_type(8))) short short8;   // 8 bf16 = 4 VGPRs
typedef __attribute__((ext_vector_type(4))) float float4v;  // MFMA C/D

// fp32 -> bf16 round-to-nearest-even
__device__ __forceinline__ u16 f2bf(float f) {
    union { float f; unsigned u; } v; v.f = f;
    unsigned r = (v.u + 0x7FFFu + ((v.u >> 16) & 1u)) >> 16;
    return (u16)r;
}

// async global->LDS, 16B per lane; LDS dest = wave-uniform base + lane*16
typedef __attribute__((address_space(3))) unsigned lds_u32_t;
typedef __attribute__((address_space(1))) const unsigned glb_u32_t;
__device__ __forceinline__ void gl2lds16(const u16* g, u16* l) {
    __builtin_amdgcn_global_load_lds((glb_u32_t*)g, (lds_u32_t*)l, 16, 0, 0);
}

// ---------------------------------------------------------------------------
// fp32 -> bf16 cast for activations (q, kv)
// ---------------------------------------------------------------------------
__global__ __launch_bounds__(256) void acast_kernel(
    const float* __restrict__ a, const float* __restrict__ b,
    u16* __restrict__ da, u16* __restrict__ db)
{
    const float* s = blockIdx.y ? b : a;
    u16* d = blockIdx.y ? db : da;
    size_t i = ((size_t)blockIdx.x * 256 + threadIdx.x) * 4;
    float4 v = *(const float4*)&s[i];
    ushort4 o = { f2bf(v.x), f2bf(v.y), f2bf(v.z), f2bf(v.w) };
    *(ushort4*)&d[i] = o;
}

// ---------------------------------------------------------------------------
// Weight transpose + cast: W[K][N] fp32 -> Wt[N][K] bf16, z selects matrix
// ---------------------------------------------------------------------------
__global__ __launch_bounds__(256) void wt_kernel(
    const float* __restrict__ Wq, const float* __restrict__ Wk,
    const float* __restrict__ Wv, const float* __restrict__ Wo,
    u16* __restrict__ dstbase)
{
    const int z = blockIdx.z;
    const float* src = (z == 0) ? Wq : (z == 1) ? Wk : (z == 2) ? Wv : Wo;
    u16* out = dstbase + (size_t)z * (KK * NN);
    const int bi = blockIdx.y, bj = blockIdx.x;  // 64x64 tile: k-block, n-block
    __shared__ float tile[64][65];
    const int t = threadIdx.x;
    #pragma unroll
    for (int p = 0; p < 4; p++) {
        int idx = p * 256 + t;
        int r = idx >> 4, c4 = (idx & 15) << 2;
        float4 v = *(const float4*)&src[(size_t)(bi * 64 + r) * NN + bj * 64 + c4];
        tile[r][c4 + 0] = v.x; tile[r][c4 + 1] = v.y;
        tile[r][c4 + 2] = v.z; tile[r][c4 + 3] = v.w;
    }
    __syncthreads();
    #pragma unroll
    for (int p = 0; p < 4; p++) {
        int idx = p * 256 + t;
        int rn = idx >> 4, c4 = (idx & 15) << 2;
        ushort4 o = { f2bf(tile[c4 + 0][rn]), f2bf(tile[c4 + 1][rn]),
                      f2bf(tile[c4 + 2][rn]), f2bf(tile[c4 + 3][rn]) };
        *(ushort4*)&out[(size_t)(bj * 64 + rn) * KK + bi * 64 + c4] = o;
    }
}

// ---------------------------------------------------------------------------
// bf16 MFMA GEMM main loop (m97 structure): C[128,128] tile, 4 waves, each
// 64x64 via 4x4 grid of 16x16x32 MFMA. BK=64, global_load_lds width-16
// staging, XOR bank swizzle on the k-colblock (slot s of row r holds global
// colblock s^(r&7)).
// A: [M,K] bf16 row-major.  Bt: [N,K] bf16 row-major (i.e. W^T).
// ---------------------------------------------------------------------------
__device__ __forceinline__ void gemm_mainloop(
    const u16* __restrict__ A, const u16* __restrict__ Bt,
    int m0, int n0, u16* As, u16* Bs, float4v (&acc)[4][4])
{
    const int tid = threadIdx.x;
    const int wave = tid >> 6, lane = tid & 63;
    const int l15 = lane & 15, lg = lane >> 4;
    const int wm = wave >> 1, wn = wave & 1;

    const int lr = lane >> 3;   // row within 8-row chunk
    const int lc = lane & 7;    // colblock slot

    for (int k0 = 0; k0 < KK; k0 += 64) {
        #pragma unroll
        for (int i = 0; i < 4; i++) {
            int chunk = wave * 4 + i;          // 0..15
            int row = chunk * 8 + lr;          // 0..127
            int gcb = lc ^ (row & 7);          // swizzled global colblock
            gl2lds16(A  + (size_t)(m0 + row) * KK + k0 + gcb * 8, As + chunk * 512);
            gl2lds16(Bt + (size_t)(n0 + row) * KK + k0 + gcb * 8, Bs + chunk * 512);
        }
        __syncthreads();

        short8 af[2][4], bf[2][4];
        #pragma unroll
        for (int kc = 0; kc < 2; kc++) {
            #pragma unroll
            for (int x = 0; x < 4; x++) {
                int ra = wm * 64 + x * 16 + l15;
                int sa = (kc * 4 + lg) ^ (ra & 7);
                af[kc][x] = *(const short8*)(As + ra * 64 + sa * 8);
                int rb = wn * 64 + x * 16 + l15;
                int sb = (kc * 4 + lg) ^ (rb & 7);
                bf[kc][x] = *(const short8*)(Bs + rb * 64 + sb * 8);
            }
        }
        #pragma unroll
        for (int mi = 0; mi < 4; mi++)
            #pragma unroll
            for (int nj = 0; nj < 4; nj++) {
                acc[mi][nj] = __builtin_amdgcn_mfma_f32_16x16x32_bf16(af[0][mi], bf[0][nj], acc[mi][nj], 0, 0, 0);
                acc[mi][nj] = __builtin_amdgcn_mfma_f32_16x16x32_bf16(af[1][mi], bf[1][nj], acc[mi][nj], 0, 0, 0);
            }
        __syncthreads();
    }
}

// ---------------------------------------------------------------------------
// QKV projection GEMM, z in {0:Q, 1:K, 2:V}. Epilogue fuses bias + RMSNorm +
// RoPE (Q,K) and writes bf16 (B,H,T,QK). Q also gets 0.125*log2(e).
// ---------------------------------------------------------------------------
__global__ __launch_bounds__(256) void qkv_gemm(
    const u16* __restrict__ qb, const u16* __restrict__ kvb,
    const u16* __restrict__ Wt,
    const float* __restrict__ bq, const float* __restrict__ bk, const float* __restrict__ bv,
    const int* __restrict__ qpos, const int* __restrict__ kpos,
    const float* __restrict__ q_scale, const float* __restrict__ k_scale,
    u16* __restrict__ qh, u16* __restrict__ kh, u16* __restrict__ vh)
{
    __shared__ u16 As[128 * 64];
    __shared__ u16 Bs[128 * 64];

    const int z = blockIdx.z;
    const u16* A        = (z == 0) ? qb : kvb;
    const u16* B        = Wt + (size_t)z * (KK * NN);
    const float* bias   = (z == 0) ? bq : (z == 1) ? bk : bv;
    const float* scl    = (z == 0) ? q_scale : k_scale;
    const int* pos_arr  = (z == 0) ? qpos : kpos;
    u16* dst            = (z == 0) ? qh : (z == 1) ? kh : vh;

    const int m0 = blockIdx.y * 128, n0 = blockIdx.x * 128;

    float4v acc[4][4];
    #pragma unroll
    for (int i = 0; i < 4; i++)
        #pragma unroll
        for (int j = 0; j < 4; j++) acc[i][j] = (float4v){0.f, 0.f, 0.f, 0.f};

    gemm_mainloop(A, B, m0, n0, As, Bs, acc);

    const int lane = threadIdx.x & 63, wave = threadIdx.x >> 6;
    const int l15 = lane & 15, lg = lane >> 4;
    const int wm = wave >> 1, wn = wave & 1;
    const int mbase = m0 + wm * 64;
    const int nbase = n0 + wn * 64;
    const int h = nbase >> 6;

    // per-lane constants
    float bia[4], sc[4];
    #pragma unroll
    for (int nj = 0; nj < 4; nj++) {
        bia[nj] = bias[nbase - (h << 6) + h * 64 + nj * 16 + l15];  // = bias[h*64+c]
        sc[nj]  = 1.0f + scl[nj * 16 + l15];
    }
    // RoPE inverse timescales for this lane's two low cols (j = p*16+l15)
    float invts[2];
    #pragma unroll
    for (int p = 0; p < 2; p++)
        invts[p] = powf(10000.0f, -(float)(p * 16 + l15) * (1.0f / 32.0f));

    const float QMUL = 0.125f * 1.44269504088896340736f;

    #pragma unroll
    for (int mi = 0; mi < 4; mi++) {
        #pragma unroll
        for (int r = 0; r < 4; r++) {
            const int m = mbase + mi * 16 + lg * 4 + r;
            const int b = m >> 11, t = m & 2047;
            float v[4];
            #pragma unroll
            for (int nj = 0; nj < 4; nj++) v[nj] = acc[mi][nj][r] + bia[nj];

            if (z < 2) {
                float ss = v[0]*v[0] + v[1]*v[1] + v[2]*v[2] + v[3]*v[3];
                ss += __shfl_xor(ss, 1);
                ss += __shfl_xor(ss, 2);
                ss += __shfl_xor(ss, 4);
                ss += __shfl_xor(ss, 8);
                float rn = rsqrtf(ss * (1.0f / 64.0f) + 1e-6f);
                #pragma unroll
                for (int nj = 0; nj < 4; nj++) v[nj] = v[nj] * rn * sc[nj];

                const float pos = (float)pos_arr[b * TT + t];
                #pragma unroll
                for (int p = 0; p < 2; p++) {
                    float ang = pos * invts[p];
                    float s = sinf(ang), c = cosf(ang);
                    float x1 = v[p], x2 = v[p + 2];
                    v[p]     = x1 * c - x2 * s;
                    v[p + 2] = x2 * c + x1 * s;
                }
                if (z == 0) {
                    #pragma unroll
                    for (int nj = 0; nj < 4; nj++) v[nj] *= QMUL;
                }
            }
            u16* op = dst + ((size_t)((b * HH + h) * TT + t)) * QKD + l15;
            #pragma unroll
            for (int nj = 0; nj < 4; nj++) op[nj * 16] = f2bf(v[nj]);
        }
    }
}

// ---------------------------------------------------------------------------
// Output projection GEMM: attn_b[M,K] bf16 @ Wo_t[N,K]^T + bo -> out fp32
// ---------------------------------------------------------------------------
__global__ __launch_bounds__(256) void out_gemm(
    const u16* __restrict__ A, const u16* __restrict__ Bt,
    const float* __restrict__ bo, float* __restrict__ out)
{
    __shared__ u16 As[128 * 64];
    __shared__ u16 Bs[128 * 64];

    const int m0 = blockIdx.y * 128, n0 = blockIdx.x * 128;

    float4v acc[4][4];
    #pragma unroll
    for (int i = 0; i < 4; i++)
        #pragma unroll
        for (int j = 0; j < 4; j++) acc[i][j] = (float4v){0.f, 0.f, 0.f, 0.f};

    gemm_mainloop(A, Bt, m0, n0, As, Bs, acc);

    const int lane = threadIdx.x & 63, wave = threadIdx.x >> 6;
    const int l15 = lane & 15, lg = lane >> 4;
    const int wm = wave >> 1, wn = wave & 1;
    const int mbase = m0 + wm * 64;
    const int nbase = n0 + wn * 64;

    float bov[4];
    #pragma unroll
    for (int nj = 0; nj < 4; nj++) bov[nj] = bo[nbase + nj * 16 + l15];

    #pragma unroll
    for (int mi = 0; mi < 4; mi++)
        #pragma unroll
        for (int r = 0; r < 4; r++) {
            const int m = mbase + mi * 16 + lg * 4 + r;
            float* op = out + (size_t)m * NN + nbase + l15;
            #pragma unroll
            for (int nj = 0; nj < 4; nj++)
                op[nj * 16] = acc[mi][nj][r] + bov[nj];
        }
}

// ---------------------------------------------------------------------------
// MFMA flash attention, causal (unchanged from round 2 except bf16 output).
// ---------------------------------------------------------------------------
#define LSTR 72

__global__ __launch_bounds__(256) void attn_mfma(
    const u16* __restrict__ qh, const u16* __restrict__ kh,
    const u16* __restrict__ vh, const float* __restrict__ head_scale,
    u16* __restrict__ out)
{
    __shared__ u16 Ks[64 * LSTR];
    __shared__ u16 Vt[64 * LSTR];
    __shared__ u16 Ps[4][16 * LSTR];

    const int b = blockIdx.z, h = blockIdx.y, qt = blockIdx.x;
    const int t0 = qt * 64;
    const int tid  = threadIdx.x;
    const int wave = tid >> 6, lane = tid & 63;
    const int l15 = lane & 15, lg = lane >> 4;

    const size_t bh_off = (size_t)(b * HH + h) * TT * QKD;
    const u16* qbh = qh + bh_off;
    const u16* kbh = kh + bh_off;
    const u16* vbh = vh + bh_off;

    short8 qfrag[2];
    #pragma unroll
    for (int kc = 0; kc < 2; kc++)
        qfrag[kc] = *(const short8*)(qbh + (size_t)(t0 + wave * 16 + l15) * QKD
                                      + kc * 32 + lg * 8);

    float4v o_acc[4];
    #pragma unroll
    for (int nt = 0; nt < 4; nt++) o_acc[nt] = (float4v){0.f, 0.f, 0.f, 0.f};
    float m_run[4] = {-INFINITY, -INFINITY, -INFINITY, -INFINITY};
    float l_run[4] = {0.f, 0.f, 0.f, 0.f};

    for (int j0 = 0; j0 <= t0; j0 += 64) {
        #pragma unroll
        for (int r = 0; r < 2; r++) {
            int idx = r * 256 + tid;
            int row = idx >> 3, cb = (idx & 7) * 8;
            short8 k8 = *(const short8*)(kbh + (size_t)(j0 + row) * QKD + cb);
            *(short8*)&Ks[row * LSTR + cb] = k8;

            int j   = tid & 63;
            int dv0 = (tid >> 6) * 8 + r * 32;
            short8 v8 = *(const short8*)(vbh + (size_t)(j0 + j) * QKD + dv0);
            #pragma unroll
            for (int i = 0; i < 8; i++)
                Vt[(dv0 + i) * LSTR + j] = (u16)v8[i];
        }
        __syncthreads();

        float4v sarr[4];
        #pragma unroll
        for (int nt = 0; nt < 4; nt++) {
            float4v s = (float4v){0.f, 0.f, 0.f, 0.f};
            #pragma unroll
            for (int kc = 0; kc < 2; kc++) {
                short8 bfrag = *(const short8*)&Ks[(nt * 16 + l15) * LSTR + kc * 32 + lg * 8];
                s = __builtin_amdgcn_mfma_f32_16x16x32_bf16(qfrag[kc], bfrag, s, 0, 0, 0);
            }
            sarr[nt] = s;
        }

        const int qbase = t0 + wave * 16 + lg * 4;
        if (j0 == t0) {
            #pragma unroll
            for (int nt = 0; nt < 4; nt++) {
                int jkey = j0 + nt * 16 + l15;
                #pragma unroll
                for (int r = 0; r < 4; r++)
                    if (jkey > qbase + r) sarr[nt][r] = -INFINITY;
            }
        }

        float alpha[4], rowsum[4];
        #pragma unroll
        for (int r = 0; r < 4; r++) {
            float m = fmaxf(fmaxf(sarr[0][r], sarr[1][r]), fmaxf(sarr[2][r], sarr[3][r]));
            m = fmaxf(m, __shfl_xor(m, 1));
            m = fmaxf(m, __shfl_xor(m, 2));
            m = fmaxf(m, __shfl_xor(m, 4));
            m = fmaxf(m, __shfl_xor(m, 8));
            float m_new = fmaxf(m_run[r], m);
            alpha[r] = exp2f(m_run[r] - m_new);
            m_run[r] = m_new;
            rowsum[r] = 0.f;
        }
        u16* pw = Ps[wave];
        #pragma unroll
        for (int nt = 0; nt < 4; nt++) {
            #pragma unroll
            for (int r = 0; r < 4; r++) {
                float p = exp2f(sarr[nt][r] - m_run[r]);
                rowsum[r] += p;
                pw[(lg * 4 + r) * LSTR + nt * 16 + l15] = f2bf(p);
            }
        }
        #pragma unroll
        for (int r = 0; r < 4; r++) {
            float rs = rowsum[r];
            rs += __shfl_xor(rs, 1);
            rs += __shfl_xor(rs, 2);
            rs += __shfl_xor(rs, 4);
            rs += __shfl_xor(rs, 8);
            l_run[r] = l_run[r] * alpha[r] + rs;
        }
        #pragma unroll
        for (int nt = 0; nt < 4; nt++)
            #pragma unroll
            for (int r = 0; r < 4; r++)
                o_acc[nt][r] *= alpha[r];

        short8 pf[2];
        #pragma unroll
        for (int kc = 0; kc < 2; kc++)
            pf[kc] = *(const short8*)&pw[l15 * LSTR + kc * 32 + lg * 8];
        #pragma unroll
        for (int nt = 0; nt < 4; nt++) {
            #pragma unroll
            for (int kc = 0; kc < 2; kc++) {
                short8 vfrag = *(const short8*)&Vt[(nt * 16 + l15) * LSTR + kc * 32 + lg * 8];
                o_acc[nt] = __builtin_amdgcn_mfma_f32_16x16x32_bf16(pf[kc], vfrag, o_acc[nt], 0, 0, 0);
            }
        }
        __syncthreads();
    }

    const float hs = 1.0f + head_scale[h];
    #pragma unroll
    for (int r = 0; r < 4; r++) {
        const int q = t0 + wave * 16 + lg * 4 + r;
        const float f = hs / l_run[r];
        u16* op = out + ((size_t)(b * TT + q) * NN) + h * QKD + l15;
        #pragma unroll
        for (int nt = 0; nt < 4; nt++)
            op[nt * 16] = f2bf(o_acc[nt][r] * f);
    }
}

// ---------------------------------------------------------------------------
extern "C" void kernel_launch(void* const* d_in, const int* in_sizes, int n_in,
                              void* d_out, int out_size, void* d_ws, size_t ws_size,
                              hipStream_t stream)
{
    const float* q          = (const float*)d_in[0];
    const float* kv         = (const float*)d_in[1];
    /* d_in[2] = causal mask -- handled analytically */
    const int*   qpos       = (const int*)d_in[3];
    const int*   kpos       = (const int*)d_in[4];
    const float* Wq         = (const float*)d_in[5];
    const float* bq         = (const float*)d_in[6];
    const float* Wk         = (const float*)d_in[7];
    const float* bk         = (const float*)d_in[8];
    const float* Wv         = (const float*)d_in[9];
    const float* bv         = (const float*)d_in[10];
    const float* q_scale    = (const float*)d_in[11];
    const float* k_scale    = (const float*)d_in[12];
    const float* head_scale = (const float*)d_in[13];
    const float* Wo         = (const float*)d_in[14];
    const float* bo         = (const float*)d_in[15];
    float* out = (float*)d_out;

    // workspace layout (bytes):
    //   [  0 MB, 16 MB)  qb    (M,K) bf16
    //   [ 16 MB, 32 MB)  kvb   (M,K) bf16
    //   [ 32 MB, 40 MB)  Wt    4 x (N,K) bf16 transposed: Wq,Wk,Wv,Wo
    //   [ 40 MB, 56 MB)  qh_b  (B,H,T,QK) bf16
    //   [ 56 MB, 72 MB)  kh_b
    //   [ 72 MB, 88 MB)  vh_b
    //   [ 88 MB,104 MB)  attn_b (B,T,N) bf16
    char* ws = (char*)d_ws;
    u16* qb     = (u16*)(ws);
    u16* kvb    = (u16*)(ws + (16u << 20));
    u16* Wt     = (u16*)(ws + (32u << 20));
    u16* qh_b   = (u16*)(ws + (40u << 20));
    u16* kh_b   = (u16*)(ws + (56u << 20));
    u16* vh_b   = (u16*)(ws + (72u << 20));
    u16* attn_b = (u16*)(ws + (88u << 20));

    // 1. cast activations to bf16
    acast_kernel<<<dim3(MM * DD / (256 * 4), 2), 256, 0, stream>>>(q, kv, qb, kvb);
    // 2. transpose+cast the four weight matrices
    wt_kernel<<<dim3(16, 16, 4), 256, 0, stream>>>(Wq, Wk, Wv, Wo, Wt);
    // 3. fused QKV projection + bias + RMSNorm + RoPE -> (B,H,T,QK) bf16
    qkv_gemm<<<dim3(NN / 128, MM / 128, 3), 256, 0, stream>>>(
        qb, kvb, Wt, bq, bk, bv, qpos, kpos, q_scale, k_scale, qh_b, kh_b, vh_b);
    // 4. causal MFMA flash attention + head_scale -> (B,T,N) bf16
    attn_mfma<<<dim3(TT / 64, HH, BB), 256, 0, stream>>>(qh_b, kh_b, vh_b, head_scale, attn_b);
    // 5. output projection + bias -> fp32
    out_gemm<<<dim3(NN / 128, MM / 128), 256, 0, stream>>>(attn_b, Wt + (size_t)3 * KK * NN, bo, out);
}